// Round 21
// baseline (241.576 us; speedup 1.0000x reference)
//
#include <hip/hip_runtime.h>
#include <cstddef>
#include <cstdint>

namespace {

constexpr int   kN = 512;
constexpr int   kB = 64;
constexpr float kAlpha = 0.8f;
constexpr float kKexp = 144.26950408889634f;    // (1/gamma) * log2(e)
constexpr float kGLn2 = 0.006931471805599453f;  // gamma * ln(2) = 1/kKexp
constexpr float kWexp = 0.07213475204444817f;   // G * log2(e)
constexpr float kZBig = -1.4426950408889634e10f; // -kKexp * 1e8 (BIG in z-units)

constexpr int W     = 8;     // waves per block
constexpr int DELTA = 8;     // global steps between block barriers
constexpr int LAM   = 72;    // per-wave lag (63 skew + DELTA + 1)
constexpr int SMAX  = 318;   // last local PAIR-step per wave (inclusive)
constexpr int NSUP  = 103;   // supersteps cover g = 0..823 >= 822
constexpr int BUFP  = 336;   // pair entries per band buffer (>= SMAX+2)

// result lane i = src[i-1] for i>=1; lane 0 = oldv[0]  (wave_shr:1 fold)
__device__ __forceinline__ float dpp_oldshr1(float oldv, float src) {
    const int oi = __builtin_bit_cast(int, oldv);
    const int si = __builtin_bit_cast(int, src);
    const int r  = __builtin_amdgcn_update_dpp(oi, si, 0x138, 0xF, 0xF, false);
    return __builtin_bit_cast(float, r);
}

// Single forward pass computing (z, Rdot), z = -k*R (softmin = softmax in
// z-units: z_sm = zmax + log2(ss)); Rdot = JVP in direction Omega=(i-j)^2.
// PAIR version: lane u at local pair-step t computes cols {2(t-u), 2(t-u)+1}
// of row 64w+u serially in registers — fixed slot overhead (boundary LDS,
// DPP folds, rolls, loop) amortized over 2 columns; gsteps 1086->823 and
// barriers halve vs the 1-col/slot r17 structure. B-pair (row above, both
// cols) = lane u-1's previous-slot pair via DPP old-fold (lane 0 receives the
// boundary buffer pair through 'old'); A(j0) = previous slot's B1 (register
// roll); A(j1)=B0; C(j1)=z0 in-slot. Race proof unchanged from r17 (LAM=72,
// DELTA=8): canonical (lane63) pair write is one superstep before the
// consumer's fold-read. x pipeline depth 2 at pair granularity: index t+2-u.
__global__ __launch_bounds__(512, 2)
void dilate_jvp_pair(const float* __restrict__ input,
                     const float* __restrict__ target,
                     float* __restrict__ partials,
                     int b0)
{
    __shared__ float  sx[kN + 16];
    __shared__ float4 buf[W + 1][BUFP];
    __shared__ float  sred[W];

    const int tid = (int)threadIdx.x;
    const int w = tid >> 6, u = tid & 63;
    const bool topw = (w == 0);
    const int b = b0 + (int)blockIdx.x;
    const int sOff = w * LAM;

    sx[tid] = input[(size_t)b * kN + tid];
    if (tid < 16) sx[kN + tid] = 0.0f;
    for (int i = tid; i < BUFP; i += 512)
        buf[0][i] = make_float4(kZBig, 0.0f, kZBig, 0.0f);
    const float tk = target[(size_t)b * kN + tid];

    // normalized exponential time weight for row tid (z-folded: wkz = -k*wk)
    float ew = exp2f(kWexp * (float)tid);
    float es = ew;
    #pragma unroll
    for (int off = 32; off; off >>= 1) es += __shfl_xor(es, off);
    if (u == 0) sred[w] = es;
    __syncthreads();
    float tot = 0.0f;
    #pragma unroll
    for (int q = 0; q < W; ++q) tot += sred[q];
    const float wkz = ew * (512.0f / tot) * (-kKexp);

    // ================= forward soft-DTW with dual (JVP), z-space ============
    float C0 = kZBig, C0d = 0.0f;                 // own row, col j0-1
    float B0 = kZBig, B0d = 0.0f;                 // row above, col j0
    float B1 = kZBig, B1d = 0.0f;                 // row above, col j1
    float pA = (topw && u == 0) ? 0.0f : kZBig;   // row above, col j0-1
    float pAd = 0.0f;
    const float2* __restrict__ sxp = reinterpret_cast<const float2*>(sx);
    float2 xp = sxp[0], xpn = sxp[(u == 0) ? 1 : 0];
    float fdr = (float)(64 * w + 3 * u);          // i-j at col j0; -2 per slot
    const float4* __restrict__ bufP4 = buf[w];
    float4* __restrict__ bufN4 = buf[w + 1];

#define PAIR_CELLS(VALID_CHECKED)                                           \
    const float zm0 = fmaxf(B0, fmaxf(pA, C0));                             \
    const float eA0 = exp2f(pA - zm0);                                      \
    const float eB0 = exp2f(B0 - zm0);                                      \
    const float eC0 = exp2f(C0 - zm0);                                      \
    const float ss0 = eA0 + eB0 + eC0;                                      \
    const float ri0 = __builtin_amdgcn_rcpf(ss0);                           \
    const float dx0 = tk - xp.x;                                            \
    float z0 = fmaf(wkz * dx0, dx0, zm0 + __log2f(ss0));                    \
    const float sd0 = fmaf(eA0, pAd, fmaf(eB0, B0d, eC0 * C0d));            \
    float d0 = fmaf(ri0, sd0, fdr * fdr);                                   \
    if (VALID_CHECKED) { z0 = valid ? z0 : kZBig; d0 = valid ? d0 : 0.0f; } \
    const float zm1 = fmaxf(B1, fmaxf(B0, z0));                             \
    const float eA1 = exp2f(B0 - zm1);                                      \
    const float eB1 = exp2f(B1 - zm1);                                      \
    const float eC1 = exp2f(z0 - zm1);                                      \
    const float ss1 = eA1 + eB1 + eC1;                                      \
    const float ri1 = __builtin_amdgcn_rcpf(ss1);                           \
    const float dx1 = tk - xp.y;                                            \
    float z1 = fmaf(wkz * dx1, dx1, zm1 + __log2f(ss1));                    \
    const float fd1 = fdr - 1.0f;                                           \
    const float sd1 = fmaf(eA1, B0d, fmaf(eB1, B1d, eC1 * d0));             \
    float d1 = fmaf(ri1, sd1, fd1 * fd1);                                   \
    if (VALID_CHECKED) { z1 = valid ? z1 : kZBig; d1 = valid ? d1 : 0.0f; } \
    C0 = z1; C0d = d1;                                                      \
    pA = B1; pAd = B1d;

    for (int m = 0; m < NSUP; ++m) {
        const int base = m * DELTA - sOff;
        if (base >= 64 && base <= 248) {
            // ---------- FULL: every lane valid for all 8 slots ----------
            #pragma unroll
            for (int dg = 0; dg < DELTA; ++dg) {
                const int t = base + dg;
                const bool valid = true; (void)valid;
                PAIR_CELLS(false)
                bufN4[t - u] = make_float4(z0, d0, z1, d1);
                const float4 rn = bufP4[t + 1];
                B0 = dpp_oldshr1(rn.x, z0); B0d = dpp_oldshr1(rn.y, d0);
                B1 = dpp_oldshr1(rn.z, z1); B1d = dpp_oldshr1(rn.w, d1);
                xp = xpn;
                xpn = sxp[t + 2 - u];
                fdr -= 2.0f;
            }
        } else if (base >= -DELTA && base <= SMAX) {
            // ---------- CHECKED: entry/exit ramps ----------
            #pragma unroll
            for (int dg = 0; dg < DELTA; ++dg) {
                const int t = base + dg;
                if (t == -1) {
                    const float4 r0 = bufP4[0];
                    B0 = dpp_oldshr1(r0.x, kZBig); B0d = dpp_oldshr1(r0.y, 0.0f);
                    B1 = dpp_oldshr1(r0.z, kZBig); B1d = dpp_oldshr1(r0.w, 0.0f);
                } else if (t >= 0 && t <= SMAX) {
                    const int p = t - u;
                    const bool valid = (p >= 0) & (p <= 255);
                    PAIR_CELLS(true)
                    if (p >= 0) bufN4[p] = make_float4(z0, d0, z1, d1);
                    const float4 rn = bufP4[t + 1];
                    B0 = dpp_oldshr1(rn.x, z0); B0d = dpp_oldshr1(rn.y, d0);
                    B1 = dpp_oldshr1(rn.z, z1); B1d = dpp_oldshr1(rn.w, d1);
                    xp = xpn;
                    int cc = t + 2 - u;
                    cc = cc < 0 ? 0 : (cc > 257 ? 257 : cc);
                    xpn = sxp[cc];
                    fdr -= 2.0f;
                }
            }
        }
        __syncthreads();
    }
#undef PAIR_CELLS

    // tid 511 (wave 7, lane 63) holds z[512][512] and Rdot[512][512]
    if (tid == 511) {
        const float rnn = C0 * (-kGLn2);          // R = -z * gamma*ln2
        const float temporal = C0d * (1.0f / (512.0f * 512.0f));
        partials[b] = (kAlpha * rnn + (1.0f - kAlpha) * temporal)
                    * (1.0f / (float)kB);
    }
}

__global__ void dilate_finalize(const float* __restrict__ partials,
                                float* __restrict__ out) {
    float v = partials[threadIdx.x];   // 64 threads = one wave
    #pragma unroll
    for (int off = 32; off > 0; off >>= 1) v += __shfl_down(v, off);
    if (threadIdx.x == 0) out[0] = v;
}

} // namespace

extern "C" void kernel_launch(void* const* d_in, const int* in_sizes, int n_in,
                              void* d_out, int out_size, void* d_ws, size_t ws_size,
                              hipStream_t stream) {
    (void)in_sizes; (void)n_in; (void)out_size; (void)ws_size;
    const float* input  = (const float*)d_in[0];
    const float* target = (const float*)d_in[1];
    float* out      = (float*)d_out;
    float* partials = (float*)d_ws;    // kB floats

    hipLaunchKernelGGL(dilate_jvp_pair, dim3(kB), dim3(512), 0, stream,
                       input, target, partials, 0);
    hipLaunchKernelGGL(dilate_finalize, dim3(1), dim3(64), 0, stream,
                       partials, out);
}

// Round 22
// 201.885 us; speedup vs baseline: 1.1966x; 1.1966x over previous
//
#include <hip/hip_runtime.h>
#include <cstddef>
#include <cstdint>

namespace {

constexpr int   kN = 512;
constexpr int   kB = 64;
constexpr float kAlpha = 0.8f;
constexpr float kBig  = 1e8f;
constexpr float kKexp = 144.26950408889634f;    // (1/gamma) * log2(e)
constexpr float kGLn2 = 0.006931471805599453f;  // gamma * ln(2) = 1/kKexp
constexpr float kWexp = 0.07213475204444817f;   // G * log2(e)

constexpr int W     = 8;     // waves per block (2 per SIMD)
constexpr int DELTA = 16;    // global steps between block barriers
constexpr int LAM   = 80;    // per-wave lag (63 skew + DELTA + 1)
constexpr int SMAX  = 574;   // last local step per wave (inclusive)
constexpr int NSUP  = 71;    // supersteps cover g = 0..1135 >= 1134
constexpr int BUFE  = 592;   // boundary buffer entries per band (no wrap)

// result lane i = src[i-1] for i>=1; lane 0 = oldv[0]  (wave_shr:1 fold)
__device__ __forceinline__ float dpp_oldshr1(float oldv, float src) {
    const int oi = __builtin_bit_cast(int, oldv);
    const int si = __builtin_bit_cast(int, src);
    const int r  = __builtin_amdgcn_update_dpp(oi, si, 0x138, 0xF, 0xF, false);
    return __builtin_bit_cast(float, r);
}

// Single forward pass computing (R, Rdot): Rdot = JVP of soft-DTW in the
// direction Omega_ij = (i-j)^2; loss_temporal = Rdot[N,N]/N^2.
// 8 staggered waves per batch; wave w owns rows [64w,64w+64); lane u owns row
// 64w+u; local step s handles column c = s-u. Wave w reads boundary buf[w]
// (row 64w; buf[0] prefilled border) and writes buf[w+1] (row 64w+64 —
// all-lane writes, lane63's canonical value lands last). Canonical write of
// entry e at global step e+63+80w; consumer prefetch-read at e+79+80w —
// always separated by >=1 superstep barrier (race-free).
// x pipeline is depth 2: xjn loaded at end of step s is consumed at step s+2,
// hence index s+2-u.
__global__ __launch_bounds__(512, 2)
void dilate_jvp8(const float* __restrict__ input,
                 const float* __restrict__ target,
                 float* __restrict__ partials,
                 int b0)
{
    __shared__ float  sx[kN + 16];
    __shared__ float2 buf[W + 1][BUFE];
    __shared__ float  sred[W];

    const int tid = (int)threadIdx.x;
    const int w = tid >> 6, u = tid & 63;
    const bool topw = (w == 0);
    const int b = b0 + (int)blockIdx.x;
    const int sOff = w * LAM;

    sx[tid] = input[(size_t)b * kN + tid];
    if (tid < 16) sx[kN + tid] = 0.0f;
    for (int i = tid; i < BUFE; i += 512) buf[0][i] = make_float2(kBig, 0.0f);
    const float tk = target[(size_t)b * kN + tid];

    // normalized exponential time weight for row tid
    float ew = exp2f(kWexp * (float)tid);
    float es = ew;
    #pragma unroll
    for (int off = 32; off; off >>= 1) es += __shfl_xor(es, off);
    if (u == 0) sred[w] = es;
    __syncthreads();
    float tot = 0.0f;
    #pragma unroll
    for (int q = 0; q < W; ++q) tot += sred[q];
    const float wk = ew * (512.0f / tot);

    // ================= forward soft-DTW with dual (JVP) =================
    float C0 = kBig, C0d = 0.0f;                 // own row, previous column
    float bval = kBig, bvald = 0.0f;             // B: lane0=buf[s], else cur[u-1]
    float aval = (topw && u == 0) ? 0.0f : kBig; // A: rolls from bval
    float avald = 0.0f;
    float xj = sx[0], xjn = sx[(u == 0) ? 1 : 0];
    float fdr = (float)(64 * w + 2 * u);         // i - j, -1 per slot
    const float2* __restrict__ bufP = buf[w];
    float2* __restrict__ bufN = buf[w + 1];

    for (int m = 0; m < NSUP; ++m) {
        const int base = m * DELTA - sOff;
        if (base >= 64 && base <= 496) {
            // ---------- FULL: every lane valid for all 16 slots ----------
            #pragma unroll
            for (int dg = 0; dg < DELTA; ++dg) {
                const int s = base + dg;
                const float m0 = fminf(bval, fminf(aval, C0));
                const float mk = m0 * kKexp;
                const float eA = exp2f(fmaf(-kKexp, aval, mk));
                const float eB = exp2f(fmaf(-kKexp, bval, mk));
                const float eC = exp2f(fmaf(-kKexp, C0,   mk));
                const float ss = eA + eB + eC;
                const float ri = __builtin_amdgcn_rcpf(ss);
                const float dx = tk - xj;
                const float cur = fmaf(wk * dx, dx,
                                       fmaf(-kGLn2, __log2f(ss), m0));
                const float sd = fmaf(eA, avald, fmaf(eB, bvald, eC * C0d));
                const float curd = fmaf(ri, sd, fdr * fdr);
                C0 = cur; C0d = curd;
                bufN[s - u] = make_float2(cur, curd);
                aval = bval; avald = bvald;
                const float2 rn = bufP[s + 1];
                bval  = dpp_oldshr1(rn.x, cur);
                bvald = dpp_oldshr1(rn.y, curd);
                xj = xjn;
                xjn = sx[s + 2 - u];
                fdr -= 1.0f;
            }
        } else if (base >= -DELTA && base <= SMAX) {
            // ---------- CHECKED: entry/exit ramps ----------
            #pragma unroll
            for (int dg = 0; dg < DELTA; ++dg) {
                const int s = base + dg;
                if (s == -1) {
                    const float2 r0 = bufP[0];
                    bval  = dpp_oldshr1(r0.x, kBig);
                    bvald = dpp_oldshr1(r0.y, 0.0f);
                } else if (s >= 0 && s <= SMAX) {
                    const int c = s - u;
                    const bool valid = (c >= 0) & (c <= 511);
                    const float m0 = fminf(bval, fminf(aval, C0));
                    const float mk = m0 * kKexp;
                    const float eA = exp2f(fmaf(-kKexp, aval, mk));
                    const float eB = exp2f(fmaf(-kKexp, bval, mk));
                    const float eC = exp2f(fmaf(-kKexp, C0,   mk));
                    const float ss = eA + eB + eC;
                    const float ri = __builtin_amdgcn_rcpf(ss);
                    const float dx = tk - xj;
                    float cur = fmaf(wk * dx, dx,
                                     fmaf(-kGLn2, __log2f(ss), m0));
                    const float sd = fmaf(eA, avald, fmaf(eB, bvald, eC * C0d));
                    float curd = fmaf(ri, sd, fdr * fdr);
                    cur  = valid ? cur  : kBig;
                    curd = valid ? curd : 0.0f;
                    C0 = cur; C0d = curd;
                    if (c >= 0) bufN[c] = make_float2(cur, curd);
                    aval = bval; avald = bvald;
                    const float2 rn = bufP[s + 1];
                    bval  = dpp_oldshr1(rn.x, cur);
                    bvald = dpp_oldshr1(rn.y, curd);
                    xj = xjn;
                    int cc = s + 2 - u;
                    cc = cc < 0 ? 0 : (cc > 511 ? 511 : cc);
                    xjn = sx[cc];
                    fdr -= 1.0f;
                }
            }
        }
        __syncthreads();
    }

    // tid 511 (wave 7, lane 63) holds R[512][512] and Rdot[512][512]
    if (tid == 511) {
        const float temporal = C0d * (1.0f / (512.0f * 512.0f));
        partials[b] = (kAlpha * C0 + (1.0f - kAlpha) * temporal)
                    * (1.0f / (float)kB);
    }
}

__global__ void dilate_finalize(const float* __restrict__ partials,
                                float* __restrict__ out) {
    float v = partials[threadIdx.x];   // 64 threads = one wave
    #pragma unroll
    for (int off = 32; off > 0; off >>= 1) v += __shfl_down(v, off);
    if (threadIdx.x == 0) out[0] = v;
}

} // namespace

extern "C" void kernel_launch(void* const* d_in, const int* in_sizes, int n_in,
                              void* d_out, int out_size, void* d_ws, size_t ws_size,
                              hipStream_t stream) {
    (void)in_sizes; (void)n_in; (void)out_size; (void)ws_size;
    const float* input  = (const float*)d_in[0];
    const float* target = (const float*)d_in[1];
    float* out      = (float*)d_out;
    float* partials = (float*)d_ws;    // kB floats

    hipLaunchKernelGGL(dilate_jvp8, dim3(kB), dim3(512), 0, stream,
                       input, target, partials, 0);
    hipLaunchKernelGGL(dilate_finalize, dim3(1), dim3(64), 0, stream,
                       partials, out);
}